// Round 1
// 366.853 us; speedup vs baseline: 1.0131x; 1.0131x over previous
//
#include <hip/hip_runtime.h>

#define NN 100000
#define NE 1600000
#define NBK 391  // buckets of 256 nodes
#define BSH 8    // bucket = dst >> 8
#define MPAD 100096  // NN padded to 128-row tiles (782*128)
#define SCB 391      // ceil(NE/4096) scatter blocks
#define CAP 5120     // padded slots per bucket (expected max ~4.3K)

typedef unsigned short ushortT;
typedef unsigned long long ull;
using sh8 = __attribute__((ext_vector_type(8))) short;   // 8 bf16 (4 VGPR) MFMA frag
using f4  = __attribute__((ext_vector_type(4))) float;   // MFMA accumulator

// ---------------- bf16 helpers ----------------

__device__ __forceinline__ unsigned short bfr(float f) {
  unsigned u = __float_as_uint(f);
  u += 0x7FFF + ((u >> 16) & 1);
  return (unsigned short)(u >> 16);
}
__device__ __forceinline__ float bf2f(unsigned short h) {
  return __uint_as_float(((unsigned)h) << 16);
}
__device__ __forceinline__ void acc8(const uint4 v, float* a) {
  a[0] += __uint_as_float(v.x << 16);
  a[1] += __uint_as_float(v.x & 0xFFFF0000u);
  a[2] += __uint_as_float(v.y << 16);
  a[3] += __uint_as_float(v.y & 0xFFFF0000u);
  a[4] += __uint_as_float(v.z << 16);
  a[5] += __uint_as_float(v.z & 0xFFFF0000u);
  a[6] += __uint_as_float(v.w << 16);
  a[7] += __uint_as_float(v.w & 0xFFFF0000u);
}
__device__ __forceinline__ sh8 hi8(const float4 a, const float4 b) {
  sh8 r;
  r[0] = (short)bfr(a.x); r[1] = (short)bfr(a.y);
  r[2] = (short)bfr(a.z); r[3] = (short)bfr(a.w);
  r[4] = (short)bfr(b.x); r[5] = (short)bfr(b.y);
  r[6] = (short)bfr(b.z); r[7] = (short)bfr(b.w);
  return r;
}

// ---------------- W pack helper ----------------
// Bp[((ks*CG + g)*64 + lane)*8 + j]; k=(ks&3)*32+(lane>>4)*8+j, n=g*16+(lane&15)
// hi for ks<4, lo residue for ks>=4.  (W stays split: keeps the weight error
// term at 2^-18 while activations carry the accepted 2^-9.)

template <int COUT>
__device__ __forceinline__ void packone(const float* __restrict__ W,
                                        ushortT* __restrict__ Bp, int i) {
  const int j = i & 7;
  const int l = (i >> 3) & 63;
  const int rest = i >> 9;
  const int g = rest % (COUT / 16);
  const int ks = rest / (COUT / 16);
  const int k = (ks & 3) * 32 + (l >> 4) * 8 + j;
  const int n = g * 16 + (l & 15);
  const float v = W[k * COUT + n];
  const unsigned short h = bfr(v);
  Bp[i] = (ks < 4) ? h : bfr(v - bf2f(h));
}

// ---------------- fused scatter (padded buckets) + weight pack ---------------
// Pairs packed to 4 B: (src << 8) | (dst & 255). src < 2^17, off 8 bits.

__global__ __launch_bounds__(256) void k_scatterpack(
    const int* __restrict__ src, const int* __restrict__ dst,
    int* __restrict__ cursor, unsigned* __restrict__ pairArr,
    const float* __restrict__ W1, const float* __restrict__ W2,
    const float* __restrict__ W3, ushortT* __restrict__ Bp1,
    ushortT* __restrict__ Bp2, ushortT* __restrict__ Bp3) {
  if (blockIdx.x >= SCB) {
    const int i = (blockIdx.x - SCB) * 256 + threadIdx.x;  // 0..81919
    if (i < 32768) packone<128>(W1, Bp1, i);
    else if (i < 65536) packone<128>(W2, Bp2, i - 32768);
    else packone<64>(W3, Bp3, i - 65536);
    return;
  }
  __shared__ int lcnt[512];   // NBK padded to 512 (zeros beyond) for paired scan
  __shared__ int lbase[512];
  __shared__ int lrank[NBK];
  __shared__ int bbase[NBK];
  __shared__ int sd2[256];
  __shared__ unsigned sorted[4096];
  __shared__ int target[4096];
  const int t = threadIdx.x;
  for (int i = t; i < 512; i += 256) lcnt[i] = 0;
  for (int i = t; i < NBK; i += 256) lrank[i] = 0;
  __syncthreads();
  const int base = blockIdx.x * 4096;
  int rs[16], rd[16];
#pragma unroll
  for (int q = 0; q < 16; q++) {
    int e = base + t + 256 * q;
    rs[q] = (e < NE) ? src[e] : -1;
    rd[q] = (e < NE) ? dst[e] : -1;
    if (rd[q] >= 0) atomicAdd(&lcnt[rd[q] >> BSH], 1);
  }
  __syncthreads();
  // 256-wide paired exclusive scan of lcnt[0..511]
  const int s0 = lcnt[2 * t];
  const int s1 = lcnt[2 * t + 1];
  sd2[t] = s0 + s1;
  __syncthreads();
  for (int off = 1; off < 256; off <<= 1) {
    int x = (t >= off) ? sd2[t - off] : 0;
    __syncthreads();
    sd2[t] += x;
    __syncthreads();
  }
  const int epair = sd2[t] - (s0 + s1);
  lbase[2 * t] = epair;
  lbase[2 * t + 1] = epair + s0;
  __syncthreads();
  for (int i = t; i < NBK; i += 256)
    if (lcnt[i] > 0) bbase[i] = atomicAdd(&cursor[i], lcnt[i]);
  __syncthreads();
#pragma unroll
  for (int q = 0; q < 16; q++) {
    if (rd[q] >= 0) {
      int b = rd[q] >> BSH;
      int r = atomicAdd(&lrank[b], 1);
      int slot = lbase[b] + r;
      sorted[slot] = ((unsigned)rs[q] << 8) | ((unsigned)rd[q] & 255u);
      target[slot] = b * CAP + bbase[b] + r;  // padded-bucket placement
    }
  }
  __syncthreads();
  const int n = min(4096, NE - base);
  for (int s = t; s < n; s += 256) pairArr[target[s]] = sorted[s];
}

// ---------------- CSR build: one block (256 thr) per 256-node bucket ---------
// thread t owns node n0+t. Count via LDS atomics, 256-wide Hillis-Steele
// scan for intra-bucket offsets, then col fill via LDS cursors.

__global__ __launch_bounds__(256) void k_buildcsr(const unsigned* __restrict__ pairArr,
                                                  const int* __restrict__ cnt,
                                                  float* __restrict__ dinv,
                                                  int* __restrict__ rowptr,
                                                  int* __restrict__ col) {
  __shared__ int lc[256];
  __shared__ int sd[256];
  __shared__ int bc[NBK];
  const int t = threadIdx.x;
  const int b = blockIdx.x;
  const int n0 = b << BSH;
  for (int i = t; i < NBK; i += 256) bc[i] = cnt[i];
  lc[t] = 0;
  __syncthreads();
  // ebeg = sum of bucket counts before b (parallel partial + tree reduce)
  int partial = 0;
  for (int i = t; i < b; i += 256) partial += bc[i];
  sd[t] = partial;
  __syncthreads();
  for (int off = 128; off > 0; off >>= 1) {
    if (t < off) sd[t] += sd[t + off];
    __syncthreads();
  }
  const int ebeg = sd[0];
  const int myCnt = bc[b];
  __syncthreads();
  const unsigned* pb = pairArr + (size_t)b * CAP;
  for (int i = t; i < myCnt; i += 256)
    atomicAdd(&lc[pb[i] & 255u], 1);
  __syncthreads();
  const int v = lc[t];
  sd[t] = v;
  __syncthreads();
  for (int off = 1; off < 256; off <<= 1) {
    int x = (t >= off) ? sd[t - off] : 0;
    __syncthreads();
    sd[t] += x;
    __syncthreads();
  }
  const int excl = sd[t] - v;  // exclusive within bucket
  lc[t] = excl;                // cursor
  const int node = n0 + t;
  if (node < NN) {
    rowptr[node] = ebeg + excl;
    dinv[node] = rsqrtf(1.0f + (float)v);  // self-loop => deg >= 1
  }
  if (b == 0 && t == 0) rowptr[NN] = NE;
  __syncthreads();
  for (int i = t; i < myCnt; i += 256) {
    unsigned p = pb[i];
    int d = (int)(p & 255u);
    int srcv = (int)(p >> 8);
    int pos = atomicAdd(&lc[d], 1);
    col[ebeg + pos] = srcv;
  }
}

// ---------------- MFMA GEMM: hs = bf16( A @ W * dinv ) -----------------------
// A = bf16 activations (layer1: fp32 X rounded in-reg). W split hi/lo, 2-pass
// per 32-wide K chunk: a@Whi + a@Wlo. RG=2, CG=4. Frag layouts: A m=lane&15,
// k=quad*8+j [m120]; B n=lane&15 [m97]; C/D col=lane&15,row=quad*4+reg [m89].

template <int COUT, bool FUSED>
__global__ __launch_bounds__(256) void k_gemmM(const ushortT* __restrict__ A,
                                               const float* __restrict__ X,
                                               const ushortT* __restrict__ Bp,
                                               const float* __restrict__ dinv,
                                               ushortT* __restrict__ hs) {
  constexpr int CGALL = COUT / 16;              // 8 or 4
  constexpr int RG = 2;                         // row-groups per wave (32 rows)
  constexpr int CG = 4;                         // col-groups per wave (64 cols)
  const int w = threadIdx.x >> 6;
  const int lane = threadIdx.x & 63;
  const int q = lane >> 4;
  const int c = lane & 15;
  int row0, cg0;
  if (COUT == 128) {
    row0 = blockIdx.x * 64 + (w & 1) * 32;     // block: 64 rows x 128 cols
    cg0 = (w >> 1) * 4;
  } else {
    row0 = blockIdx.x * 128 + w * 32;          // block: 128 rows x 64 cols
    cg0 = 0;
  }

  const ushortT* ap[RG];
  const float* xp[RG];
#pragma unroll
  for (int rg = 0; rg < RG; rg++) {
    const int row = row0 + rg * 16 + c;
    if (FUSED) xp[rg] = X + (size_t)min(row, NN - 1) * 128 + q * 8;
    else ap[rg] = A + (size_t)row * 128 + q * 8;
  }
  const ushortT* bp0 = Bp + (size_t)lane * 8;

  f4 acc[RG][CG];
#pragma unroll
  for (int i = 0; i < RG; i++)
#pragma unroll
    for (int j = 0; j < CG; j++) acc[i][j] = (f4){0.f, 0.f, 0.f, 0.f};

  sh8 ah[RG], bh[CG], bl[CG];
  sh8 nah[RG], nbh[CG], nbl[CG];

  auto loadA = [&](int kr, sh8 (&h)[RG]) {
#pragma unroll
    for (int rg = 0; rg < RG; rg++) {
      if (FUSED) {
        const float4 x0 = *reinterpret_cast<const float4*>(xp[rg] + kr * 32);
        const float4 x1 = *reinterpret_cast<const float4*>(xp[rg] + kr * 32 + 4);
        h[rg] = hi8(x0, x1);
      } else {
        h[rg] = *reinterpret_cast<const sh8*>(ap[rg] + kr * 32);
      }
    }
  };
  auto loadB = [&](int kr, sh8 (&h)[CG], sh8 (&l)[CG]) {
#pragma unroll
    for (int cg = 0; cg < CG; cg++) {
      h[cg] = *reinterpret_cast<const sh8*>(bp0 + (size_t)(kr * CGALL + cg0 + cg) * 512);
      l[cg] = *reinterpret_cast<const sh8*>(bp0 + (size_t)((4 + kr) * CGALL + cg0 + cg) * 512);
    }
  };

  loadA(0, ah);
  loadB(0, bh, bl);
#pragma unroll
  for (int kr = 0; kr < 4; kr++) {
    if (kr < 3) {
      loadA(kr + 1, nah);
      loadB(kr + 1, nbh, nbl);
    }
#pragma unroll
    for (int rg = 0; rg < RG; rg++)
#pragma unroll
      for (int cg = 0; cg < CG; cg++)
        acc[rg][cg] = __builtin_amdgcn_mfma_f32_16x16x32_bf16(ah[rg], bh[cg],
                                                              acc[rg][cg], 0, 0, 0);
#pragma unroll
    for (int rg = 0; rg < RG; rg++)
#pragma unroll
      for (int cg = 0; cg < CG; cg++)
        acc[rg][cg] = __builtin_amdgcn_mfma_f32_16x16x32_bf16(ah[rg], bl[cg],
                                                              acc[rg][cg], 0, 0, 0);
    if (kr < 3) {
#pragma unroll
      for (int rg = 0; rg < RG; rg++) ah[rg] = nah[rg];
#pragma unroll
      for (int cg = 0; cg < CG; cg++) { bh[cg] = nbh[cg]; bl[cg] = nbl[cg]; }
    }
  }

  // epilogue: scale by dinv[row], round to bf16, store
#pragma unroll
  for (int rg = 0; rg < RG; rg++) {
#pragma unroll
    for (int reg = 0; reg < 4; reg++) {
      const int row = row0 + rg * 16 + q * 4 + reg;
      if (row < NN) {
        const float dv = dinv[row];
#pragma unroll
        for (int cg = 0; cg < CG; cg++) {
          hs[(size_t)row * COUT + (cg0 + cg) * 16 + c] = bfr(acc[rg][cg][reg] * dv);
        }
      }
    }
  }
}

// ---------------- aggregation (bf16 gather, fp32 accumulate) ------------------
// One wave per node; 16 lanes x 16 B cover a 256 B row; 4 quads = 4 edges in
// parallel. Steady state: 16-edge window, 4 gathers in flight per lane (deeper
// MLP for the latency-bound gather). Output: bf16 activations.

template <bool RELU>
__global__ __launch_bounds__(256) void k_agg128(const ushortT* __restrict__ hs,
                                                const int* __restrict__ rowptr,
                                                const int* __restrict__ col,
                                                const float* __restrict__ dinv,
                                                const float* __restrict__ bias,
                                                ushortT* __restrict__ A) {
  const int gid = blockIdx.x * 256 + threadIdx.x;
  const int node = gid >> 6;  // one wave per node
  if (node >= NN) return;
  const int lane = threadIdx.x & 63;
  const int q = lane >> 4;          // quarter 0..3
  const int chb = (lane & 15) * 8;  // 8 channels per lane
  const int beg = rowptr[node];
  const int end = rowptr[node + 1];

  float a[8] = {};
  if (q == 0) {  // self-loop contribution
    const uint4 v = *reinterpret_cast<const uint4*>(hs + (long)node * 128 + chb);
    acc8(v, a);
  }

  int j = beg;
  if (j + 16 <= end) {  // 4 gathers in flight per lane
    int c0 = col[j + q];
    int c1 = col[j + 4 + q];
    int c2 = col[j + 8 + q];
    int c3 = col[j + 12 + q];
    while (true) {
      const uint4 v0 = *reinterpret_cast<const uint4*>(hs + (long)c0 * 128 + chb);
      const uint4 v1 = *reinterpret_cast<const uint4*>(hs + (long)c1 * 128 + chb);
      const uint4 v2 = *reinterpret_cast<const uint4*>(hs + (long)c2 * 128 + chb);
      const uint4 v3 = *reinterpret_cast<const uint4*>(hs + (long)c3 * 128 + chb);
      j += 16;
      const bool more = (j + 16 <= end);
      int n0, n1, n2, n3;
      if (more) {
        n0 = col[j + q]; n1 = col[j + 4 + q];
        n2 = col[j + 8 + q]; n3 = col[j + 12 + q];
      }
      acc8(v0, a);
      acc8(v1, a);
      acc8(v2, a);
      acc8(v3, a);
      if (!more) break;
      c0 = n0; c1 = n1; c2 = n2; c3 = n3;
    }
  }
  if (j + 8 <= end) {  // at most once after the 16-loop
    int c0 = col[j + q];
    int c1 = col[j + 4 + q];
    const uint4 v0 = *reinterpret_cast<const uint4*>(hs + (long)c0 * 128 + chb);
    const uint4 v1 = *reinterpret_cast<const uint4*>(hs + (long)c1 * 128 + chb);
    acc8(v0, a);
    acc8(v1, a);
    j += 8;
  }
  if (j + 4 <= end) {
    int c = col[j + q];
    const uint4 v = *reinterpret_cast<const uint4*>(hs + (long)c * 128 + chb);
    acc8(v, a);
    j += 4;
  }
  {
    const int r = end - j;  // 0..3
    if (q < r) {
      int c = col[j + q];
      const uint4 v = *reinterpret_cast<const uint4*>(hs + (long)c * 128 + chb);
      acc8(v, a);
    }
  }

#pragma unroll
  for (int i = 0; i < 8; i++) a[i] += __shfl(a[i], lane ^ 32);
#pragma unroll
  for (int i = 0; i < 8; i++) a[i] += __shfl(a[i], lane ^ 16);

  if (q == 0) {
    const float di = dinv[node];
    const float4 b0 = *reinterpret_cast<const float4*>(bias + chb);
    const float4 b1 = *reinterpret_cast<const float4*>(bias + chb + 4);
    float o[8];
    o[0] = fmaf(a[0], di, b0.x); o[1] = fmaf(a[1], di, b0.y);
    o[2] = fmaf(a[2], di, b0.z); o[3] = fmaf(a[3], di, b0.w);
    o[4] = fmaf(a[4], di, b1.x); o[5] = fmaf(a[5], di, b1.y);
    o[6] = fmaf(a[6], di, b1.z); o[7] = fmaf(a[7], di, b1.w);
    if (RELU) {
#pragma unroll
      for (int i = 0; i < 8; i++) o[i] = fmaxf(o[i], 0.f);
    }
    uint4 H;
    H.x = (unsigned)bfr(o[0]) | ((unsigned)bfr(o[1]) << 16);
    H.y = (unsigned)bfr(o[2]) | ((unsigned)bfr(o[3]) << 16);
    H.z = (unsigned)bfr(o[4]) | ((unsigned)bfr(o[5]) << 16);
    H.w = (unsigned)bfr(o[6]) | ((unsigned)bfr(o[7]) << 16);
    *reinterpret_cast<uint4*>(A + (long)node * 128 + chb) = H;
  }
}

__global__ __launch_bounds__(256) void k_agg64(const ushortT* __restrict__ hs,
                                               const int* __restrict__ rowptr,
                                               const int* __restrict__ col,
                                               const float* __restrict__ dinv,
                                               const float* __restrict__ bias,
                                               float* __restrict__ out) {
  const int gid = blockIdx.x * 256 + threadIdx.x;
  const int node = gid >> 6;
  if (node >= NN) return;
  const int lane = threadIdx.x & 63;
  const int o8 = lane >> 3;        // eighth 0..7
  const int chb = (lane & 7) * 8;  // 8 channels per lane
  const int beg = rowptr[node];
  const int end = rowptr[node + 1];

  float a[8] = {};
  if (o8 == 0) {  // self
    const uint4 v = *reinterpret_cast<const uint4*>(hs + (long)node * 64 + chb);
    acc8(v, a);
  }

  int j = beg;
  if (j + 16 <= end) {
    int c0 = col[j + o8];
    int c1 = col[j + 8 + o8];
    while (true) {
      const uint4 v0 = *reinterpret_cast<const uint4*>(hs + (long)c0 * 64 + chb);
      const uint4 v1 = *reinterpret_cast<const uint4*>(hs + (long)c1 * 64 + chb);
      j += 16;
      const bool more = (j + 16 <= end);
      int n0, n1;
      if (more) { n0 = col[j + o8]; n1 = col[j + 8 + o8]; }
      acc8(v0, a);
      acc8(v1, a);
      if (!more) break;
      c0 = n0; c1 = n1;
    }
  }
  for (; j + 8 <= end; j += 8) {
    int c = col[j + o8];
    const uint4 v = *reinterpret_cast<const uint4*>(hs + (long)c * 64 + chb);
    acc8(v, a);
  }
  {
    const int r = end - j;  // 0..7
    if (o8 < r) {
      int c = col[j + o8];
      const uint4 v = *reinterpret_cast<const uint4*>(hs + (long)c * 64 + chb);
      acc8(v, a);
    }
  }

#pragma unroll
  for (int i = 0; i < 8; i++) a[i] += __shfl(a[i], lane ^ 32);
#pragma unroll
  for (int i = 0; i < 8; i++) a[i] += __shfl(a[i], lane ^ 16);
#pragma unroll
  for (int i = 0; i < 8; i++) a[i] += __shfl(a[i], lane ^ 8);

  if (o8 == 0) {
    const float di = dinv[node];
    const float4 b0 = *reinterpret_cast<const float4*>(bias + chb);
    const float4 b1 = *reinterpret_cast<const float4*>(bias + chb + 4);
    float4 r0, r1;
    r0.x = fmaf(a[0], di, b0.x); r0.y = fmaf(a[1], di, b0.y);
    r0.z = fmaf(a[2], di, b0.z); r0.w = fmaf(a[3], di, b0.w);
    r1.x = fmaf(a[4], di, b1.x); r1.y = fmaf(a[5], di, b1.y);
    r1.z = fmaf(a[6], di, b1.z); r1.w = fmaf(a[7], di, b1.w);
    *reinterpret_cast<float4*>(out + (long)node * 64 + chb) = r0;
    *reinterpret_cast<float4*>(out + (long)node * 64 + chb + 4) = r1;
  }
}

// ---------------- launch ----------------

extern "C" void kernel_launch(void* const* d_in, const int* in_sizes, int n_in,
                              void* d_out, int out_size, void* d_ws, size_t ws_size,
                              hipStream_t stream) {
  const float* x  = (const float*)d_in[0];
  const int* ei   = (const int*)d_in[1];
  const float* W1 = (const float*)d_in[2];
  const float* b1 = (const float*)d_in[3];
  const float* W2 = (const float*)d_in[4];
  const float* b2 = (const float*)d_in[5];
  const float* W3 = (const float*)d_in[6];
  const float* b3 = (const float*)d_in[7];
  float* out = (float*)d_out;
  const int* srcp = ei;        // edge_index[0]
  const int* dstp = ei + NE;   // edge_index[1]

  char* wsb = (char*)d_ws;
  size_t off = 0;
  auto alloc = [&](size_t bytes) -> void* {
    void* p = wsb + off;
    off += (bytes + 255) & ~(size_t)255;
    return p;
  };
  ushortT* A   = (ushortT*)alloc((size_t)MPAD * 128 * 2);   // bf16 activations
  ushortT* hs  = (ushortT*)alloc((size_t)NN * 128 * 2);     // bf16 transform out
  int*   col    = (int*)alloc((size_t)NE * 4);
  int*   rowptr = (int*)alloc((size_t)(NN + 1) * 4);
  float* dinv   = (float*)alloc((size_t)NN * 4);
  int*   cursor = (int*)alloc((size_t)NBK * 4);
  ushortT* Bp1 = (ushortT*)alloc((size_t)32768 * 2);  // 8 seg x 8 cg x 512
  ushortT* Bp2 = (ushortT*)alloc((size_t)32768 * 2);
  ushortT* Bp3 = (ushortT*)alloc((size_t)16384 * 2);  // 8 seg x 4 cg x 512
  // pairArr (391*5120*4 = 8.0 MB) aliases hs (25.6 MB): build-only.
  unsigned* pairArr = (unsigned*)hs;
  (void)ws_size; (void)in_sizes; (void)n_in; (void)out_size;

  hipMemsetAsync(cursor, 0, (size_t)NBK * 4, stream);
  k_scatterpack<<<SCB + 320, 256, 0, stream>>>(srcp, dstp, cursor, pairArr,
                                               W1, W2, W3, Bp1, Bp2, Bp3);
  k_buildcsr<<<NBK, 256, 0, stream>>>(pairArr, cursor, dinv, rowptr, col);

  const int aggGrid = (NN * 64) / 256;   // 25000
  const int gemmGrid128 = MPAD / 64;     // 1564 (64-row blocks)
  const int gemmGrid64 = MPAD / 128;     // 782 (128-row blocks)

  // layer 1 (fused — reads fp32 X directly, rounds to bf16 in-reg)
  k_gemmM<128, true><<<gemmGrid128, 256, 0, stream>>>(nullptr, x, Bp1, dinv, hs);
  k_agg128<true><<<aggGrid, 256, 0, stream>>>(hs, rowptr, col, dinv, b1, A);
  // layer 2
  k_gemmM<128, false><<<gemmGrid128, 256, 0, stream>>>(A, nullptr, Bp2, dinv, hs);
  k_agg128<true><<<aggGrid, 256, 0, stream>>>(hs, rowptr, col, dinv, b2, A);
  // layer 3 (128 -> 64, no relu)
  k_gemmM<64, false><<<gemmGrid64, 256, 0, stream>>>(A, nullptr, Bp3, dinv, hs);
  k_agg64<<<aggGrid, 256, 0, stream>>>(hs, rowptr, col, dinv, b3, out);
}